// Round 13
// baseline (352.536 us; speedup 1.0000x reference)
//
#include <hip/hip_runtime.h>

// ---------------------------------------------------------------------------
// G_CAM_Module: out = gamma * (GA @ x) + x, where GA comes from a chain of
// softmaxed 64x64 Gram matrices of x and g.
//
//   A) gram_kernel  : partial Grams via MFMA f16, apply-REGIME: 256px chunk,
//                     256 thr, 33.8KB LDS (4 blocks/CU), plain staging loop,
//                     one barrier, uniform-bank-slot LDS (ROW_H=264h).
//   A') diag_stage / diag_consume: HALF-SCALE phase-isolation dispatches
//                     (read per-dispatch dur in rocprof; deleted next round).
//   B) reduce_kernel: sum 256 chunk-partials -> ex[b], eg[b]
//   C) chain_kernel : softmax chain -> M = gamma*GA   (no identity; tiny fp32)
//   D) apply_kernel : out[b] = M[b] @ x_b + x_b via MFMA f16 (fp32 residual)
// ---------------------------------------------------------------------------

typedef _Float16 h8 __attribute__((ext_vector_type(8)));
typedef float    f4 __attribute__((ext_vector_type(4)));
typedef __fp16   p2 __attribute__((ext_vector_type(2)));   // cvt_pkrtz result
typedef unsigned long long ull;

#define NB 16
#define NC 64
#define NPIX 65536
#define GRAM_CHUNK 256                  // pixels per gram block
#define NCHUNK (NPIX / GRAM_CHUNK)      // 256
#define ROW_H 264                       // halves (528B = 132 dw == 4 mod 32):
                                        // bank-slot(row,khalf) = (row+khalf)%8
                                        // -> uniform across a wave's b128 read
#define LDS_H (64 * ROW_H)              // 16896 halves = 33792 B

#define AP_NPX 256                      // apply: pixels per block
#define XT_ROW 72                       // apply: xT row stride in halves (144B)

__device__ __forceinline__ unsigned int pk(float a, float b) {
    p2 v = __builtin_amdgcn_cvt_pkrtz(a, b);
    return __builtin_bit_cast(unsigned int, v);
}

// ---- Kernel A: partial Gram matrices via MFMA, apply-regime ---------------
// grid (256, 16, 2): chunk, batch, matrix. 256 threads = 4 waves; wave w owns
// A row-block w, computes 16x64 (acc[4]); K = 256 px in 8 steps of 32.
__global__ __launch_bounds__(256) void gram_kernel(
    const float* __restrict__ x, const float* __restrict__ g,
    float* __restrict__ part)
{
    __shared__ __align__(16) _Float16 buf[LDS_H];

    const int tid = threadIdx.x;
    const int mtx = blockIdx.z;
    const float* src = (mtx ? g : x)
        + (size_t)blockIdx.y * NC * NPIX + (size_t)blockIdx.x * GRAM_CHUNK;

    const int sq = tid & 63;           // f4 col (256px = 64 f4)
    const int sr = tid >> 6;           // base row 0..3 (+4 per it)

    // ---- stage: plain loop, 16 coalesced f4 loads (apply-style) ----
    #pragma unroll
    for (int it = 0; it < 16; ++it) {
        int r = it * 4 + sr;
        f4 v = *(const f4*)(src + (size_t)r * NPIX + sq * 4);
        ull h = (ull)pk(v.x, v.y) | ((ull)pk(v.z, v.w) << 32);
        *reinterpret_cast<ull*>(&buf[r * ROW_H + sq * 4]) = h;
    }
    __syncthreads();   // the only barrier

    // ---- consume: 8 K-steps x (1 A-frag + 4 B-frags + 4 MFMA) ----
    const int w     = tid >> 6;
    const int lane  = tid & 63;
    const int l15   = lane & 15;
    const int khalf = lane >> 4;
    const int abase = (w * 16 + l15) * ROW_H;

    f4 acc[4];
    #pragma unroll
    for (int cb = 0; cb < 4; ++cb) acc[cb] = (f4){0.f, 0.f, 0.f, 0.f};

    #pragma unroll
    for (int ks = 0; ks < 8; ++ks) {
        int koff = ks * 32 + khalf * 8;
        h8 a = *reinterpret_cast<const h8*>(&buf[abase + koff]);
        #pragma unroll
        for (int cb = 0; cb < 4; ++cb) {
            h8 bf = *reinterpret_cast<const h8*>(&buf[(cb * 16 + l15) * ROW_H + koff]);
            acc[cb] = __builtin_amdgcn_mfma_f32_16x16x32_f16(a, bf, acc[cb], 0, 0, 0);
        }
    }

    float* po = part + (((size_t)blockIdx.x * NB + blockIdx.y) * 2 + mtx) * 4096;
    #pragma unroll
    for (int cb = 0; cb < 4; ++cb)
        #pragma unroll
        for (int r = 0; r < 4; ++r)
            po[(w * 16 + khalf * 4 + r) * 64 + cb * 16 + l15] = acc[cb][r];
}

// ---- A': half-scale phase diagnostics (read rocprof per-dispatch dur) -----
__global__ __launch_bounds__(256) void diag_stage(
    const float* __restrict__ x, const float* __restrict__ g,
    float* __restrict__ sink)
{
    __shared__ __align__(16) _Float16 buf[LDS_H];
    const int tid = threadIdx.x;
    const float* src = (blockIdx.z ? g : x)
        + (size_t)blockIdx.y * NC * NPIX + (size_t)blockIdx.x * GRAM_CHUNK;
    const int sq = tid & 63, sr = tid >> 6;
    float cs = 0.f;
    #pragma unroll
    for (int it = 0; it < 16; ++it) {
        int r = it * 4 + sr;
        f4 v = *(const f4*)(src + (size_t)r * NPIX + sq * 4);
        cs += v.x + v.y + v.z + v.w;                     // keep loads live
        ull h = (ull)pk(v.x, v.y) | ((ull)pk(v.z, v.w) << 32);
        *reinterpret_cast<ull*>(&buf[r * ROW_H + sq * 4]) = h;
    }
    __syncthreads();
    cs += (float)buf[((tid * 67) % LDS_H)];              // keep writes live
    sink[(size_t)(blockIdx.x + 128 * (blockIdx.y + 16 * blockIdx.z)) * 256 + tid] = cs;
}

__global__ __launch_bounds__(256) void diag_consume(float* __restrict__ sink)
{
    __shared__ __align__(16) _Float16 buf[LDS_H];
    const int tid = threadIdx.x;
    // cheap defined fill (17 b64 writes) so reads can't fold to undef
    ull seed = 0x3c003c003c003c00ull + tid;
    #pragma unroll
    for (int it = 0; it < 17; ++it) {
        int o = it * 1024 + tid * 4;
        if (o + 3 < LDS_H) *reinterpret_cast<ull*>(&buf[o]) = seed;
    }
    __syncthreads();
    const int w = tid >> 6, lane = tid & 63, l15 = lane & 15, khalf = lane >> 4;
    const int abase = (w * 16 + l15) * ROW_H;
    f4 acc[4];
    #pragma unroll
    for (int cb = 0; cb < 4; ++cb) acc[cb] = (f4){0.f, 0.f, 0.f, 0.f};
    #pragma unroll
    for (int ks = 0; ks < 8; ++ks) {
        int koff = ks * 32 + khalf * 8;
        h8 a = *reinterpret_cast<const h8*>(&buf[abase + koff]);
        #pragma unroll
        for (int cb = 0; cb < 4; ++cb) {
            h8 bf = *reinterpret_cast<const h8*>(&buf[(cb * 16 + l15) * ROW_H + koff]);
            acc[cb] = __builtin_amdgcn_mfma_f32_16x16x32_f16(a, bf, acc[cb], 0, 0, 0);
        }
    }
    float cs = 0.f;
    #pragma unroll
    for (int cb = 0; cb < 4; ++cb) cs += acc[cb][0] + acc[cb][1] + acc[cb][2] + acc[cb][3];
    sink[(size_t)(blockIdx.x + 128 * (blockIdx.y + 16 * blockIdx.z)) * 256 + tid] = cs;
}

// ---- Kernel B: reduce 256 chunk-partials -> ex, eg -------------------------
__global__ __launch_bounds__(256) void reduce_kernel(
    const float* __restrict__ part, float* __restrict__ ex, float* __restrict__ eg)
{
    const int idx = blockIdx.x * 256 + threadIdx.x;
    const int bm = idx >> 12;          // b*2 + m
    const int cd = idx & 4095;
    float s = 0.f;
    #pragma unroll 8
    for (int ch = 0; ch < NCHUNK; ++ch)
        s += part[(size_t)ch * (NB * 2 * 4096) + (size_t)bm * 4096 + cd];
    float* dst = (bm & 1) ? eg : ex;
    dst[(bm >> 1) * 4096 + cd] = s;
}

// ---- Kernel C: softmax chain -> M = gamma*GA (no identity) ----------------
__global__ __launch_bounds__(256) void chain_kernel(
    const float* __restrict__ ex, const float* __restrict__ eg,
    const float* __restrict__ gammap, float* __restrict__ M)
{
    __shared__ float A1[64][68];
    __shared__ float A2[64][68];
    __shared__ float red[64][4];

    const int b = blockIdx.x;
    const int tid = threadIdx.x;

    if (tid < 64) {
        const int c = tid;
        float r[64];
        #pragma unroll
        for (int d = 0; d < 64; ++d) r[d] = ex[b * 4096 + c * 64 + d];
        float mx = r[0];
        #pragma unroll
        for (int d = 1; d < 64; ++d) mx = fmaxf(mx, r[d]);
        float s = 0.f;
        #pragma unroll
        for (int d = 0; d < 64; ++d) { r[d] = expf(r[d] - mx); s += r[d]; }
        float inv = 1.f / s;
        #pragma unroll
        for (int d = 0; d < 64; ++d) A1[c][d] = r[d] * inv;

        #pragma unroll
        for (int d = 0; d < 64; ++d) r[d] = eg[b * 4096 + c * 64 + d];
        mx = r[0];
        #pragma unroll
        for (int d = 1; d < 64; ++d) mx = fmaxf(mx, r[d]);
        s = 0.f;
        #pragma unroll
        for (int d = 0; d < 64; ++d) { r[d] = expf(r[d] - mx); s += r[d]; }
        inv = 1.f / s;
        #pragma unroll
        for (int d = 0; d < 64; ++d) A2[c][d] = r[d] * inv;
    }
    __syncthreads();

    const int c = tid >> 2, sq = tid & 3;
    float ge[16];
    #pragma unroll
    for (int k = 0; k < 16; ++k) ge[k] = 0.f;
    for (int d = 0; d < 64; ++d) {
        float a = A1[c][d];
        const float* row = &A2[d][sq * 16];
        #pragma unroll
        for (int k = 0; k < 16; ++k) ge[k] = fmaf(a, row[k], ge[k]);
    }

    float mx = ge[0];
    #pragma unroll
    for (int k = 1; k < 16; ++k) mx = fmaxf(mx, ge[k]);
    red[c][sq] = mx;
    __syncthreads();
    float gm = fmaxf(fmaxf(red[c][0], red[c][1]), fmaxf(red[c][2], red[c][3]));
    __syncthreads();

    float gen[16];
    #pragma unroll
    for (int k = 0; k < 16; ++k) gen[k] = gm - ge[k];
    float mx2 = gen[0];
    #pragma unroll
    for (int k = 1; k < 16; ++k) mx2 = fmaxf(mx2, gen[k]);
    red[c][sq] = mx2;
    __syncthreads();
    float m2 = fmaxf(fmaxf(red[c][0], red[c][1]), fmaxf(red[c][2], red[c][3]));
    __syncthreads();

    float p[16];
    float s = 0.f;
    #pragma unroll
    for (int k = 0; k < 16; ++k) { p[k] = expf(gen[k] - m2); s += p[k]; }
    red[c][sq] = s;
    __syncthreads();
    float S = red[c][0] + red[c][1] + red[c][2] + red[c][3];

    float gam = gammap[0];
    float invS = 1.f / S;
    #pragma unroll
    for (int k = 0; k < 16; ++k) {
        int e = sq * 16 + k;
        M[b * 4096 + c * 64 + e] = gam * p[k] * invS;   // NO +I: residual in apply
    }
}

// ---- Kernel D: out[b] = M[b] @ x[b] + x[b] via MFMA ------------------------
__global__ __launch_bounds__(256) void apply_kernel(
    const float* __restrict__ x, const float* __restrict__ M,
    float* __restrict__ out)
{
    __shared__ __align__(16) _Float16 xT[AP_NPX * XT_ROW];   // 36864 B
    __shared__ __align__(16) _Float16 Ml[64 * XT_ROW];       //  9216 B

    const int tid = threadIdx.x;
    const int b = blockIdx.y;
    const int n0 = blockIdx.x * AP_NPX;
    const float* xb = x + (size_t)b * NC * NPIX + n0;

    #pragma unroll
    for (int it = 0; it < 8; ++it) {
        int e = it * 256 + tid;
        int q  = e & 63;          // f4 col (4 pixels)
        int dp = e >> 6;          // d-pair 0..31
        f4 va = *(const f4*)(xb + (size_t)(2 * dp)     * NPIX + q * 4);
        f4 vb = *(const f4*)(xb + (size_t)(2 * dp + 1) * NPIX + q * 4);
        #pragma unroll
        for (int j = 0; j < 4; ++j) {
            float aj = (j == 0) ? va.x : (j == 1) ? va.y : (j == 2) ? va.z : va.w;
            float bj = (j == 0) ? vb.x : (j == 1) ? vb.y : (j == 2) ? vb.z : vb.w;
            *reinterpret_cast<unsigned int*>(&xT[(q * 4 + j) * XT_ROW + 2 * dp]) = pk(aj, bj);
        }
    }
    const float* Mb = M + b * 4096;
    #pragma unroll
    for (int it = 0; it < 4; ++it) {
        int e = it * 256 + tid;
        int c  = e >> 4;
        int qq = e & 15;
        f4 mv = *(const f4*)(Mb + c * 64 + qq * 4);
        *reinterpret_cast<unsigned int*>(&Ml[c * XT_ROW + qq * 4])     = pk(mv.x, mv.y);
        *reinterpret_cast<unsigned int*>(&Ml[c * XT_ROW + qq * 4 + 2]) = pk(mv.z, mv.w);
    }
    __syncthreads();

    const int w    = tid >> 6;
    const int lane = tid & 63;
    const int l15  = lane & 15;
    const int kh   = lane >> 4;

    h8 bfrag[4][2];
    #pragma unroll
    for (int nb = 0; nb < 4; ++nb)
        #pragma unroll
        for (int ks = 0; ks < 2; ++ks)
            bfrag[nb][ks] = *reinterpret_cast<const h8*>(
                &xT[(w * 64 + nb * 16 + l15) * XT_ROW + ks * 32 + kh * 8]);

    f4 acc[4][4];   // [cb][nb]
    #pragma unroll
    for (int cb = 0; cb < 4; ++cb)
        #pragma unroll
        for (int nb = 0; nb < 4; ++nb) acc[cb][nb] = (f4){0.f, 0.f, 0.f, 0.f};

    #pragma unroll
    for (int cb = 0; cb < 4; ++cb) {
        #pragma unroll
        for (int ks = 0; ks < 2; ++ks) {
            h8 a = *reinterpret_cast<const h8*>(
                &Ml[(cb * 16 + l15) * XT_ROW + ks * 32 + kh * 8]);
            #pragma unroll
            for (int nb = 0; nb < 4; ++nb)
                acc[cb][nb] = __builtin_amdgcn_mfma_f32_16x16x32_f16(a, bfrag[nb][ks], acc[cb][nb], 0, 0, 0);
        }
    }

    const size_t base = (size_t)b * NC * NPIX + n0 + w * 64;
    #pragma unroll
    for (int cb = 0; cb < 4; ++cb) {
        #pragma unroll
        for (int r = 0; r < 4; ++r) {
            const int row = cb * 16 + kh * 4 + r;
            #pragma unroll
            for (int nb = 0; nb < 4; ++nb) {
                size_t idx = base + (size_t)row * NPIX + nb * 16 + l15;
                out[idx] = acc[cb][nb][r] + x[idx];
            }
        }
    }
}

extern "C" void kernel_launch(void* const* d_in, const int* in_sizes, int n_in,
                              void* d_out, int out_size, void* d_ws, size_t ws_size,
                              hipStream_t stream) {
    const float* x     = (const float*)d_in[0];
    const float* g     = (const float*)d_in[1];
    const float* gamma = (const float*)d_in[2];
    float* out = (float*)d_out;
    float* ws  = (float*)d_ws;

    float* ex = ws;                  // 16*4096 floats
    float* eg = ws + NB * 4096;      // 16*4096 floats
    float* M  = ws + 2 * NB * 4096;  // 16*4096 floats

    // d_out doubles as scratch: part = first 134 MB (256*16*2*16KB);
    // diag sinks live past 192 MB. apply fully overwrites d_out at the end.
    float* part  = out;
    float* sink1 = out + 48u * 1024 * 1024;   // 4 MB used
    float* sink2 = out + 56u * 1024 * 1024;   // 4 MB used

    gram_kernel<<<dim3(NCHUNK, NB, 2), 256, 0, stream>>>(x, g, part);
    // half-scale phase diagnostics (per-dispatch dur in rocprof; remove later)
    diag_stage<<<dim3(128, NB, 2), 256, 0, stream>>>(x, g, sink1);
    diag_consume<<<dim3(128, NB, 2), 256, 0, stream>>>(sink2);
    reduce_kernel<<<512, 256, 0, stream>>>(part, ex, eg);
    chain_kernel<<<NB, 256, 0, stream>>>(ex, eg, gamma, M);
    apply_kernel<<<dim3(NPIX / AP_NPX, NB), 256, 0, stream>>>(x, M, out);
}

// Round 15
// 267.324 us; speedup vs baseline: 1.3188x; 1.3188x over previous
//
#include <hip/hip_runtime.h>

// ---------------------------------------------------------------------------
// G_CAM_Module: out = gamma * (GA @ x) + x, where GA comes from a chain of
// softmaxed 64x64 Gram matrices of x and g.
//
//   A) gram_kernel  : partial Grams via MFMA f16. GRAM_CHUNK=512, 256 thr,
//                     one barrier. Staging ordered as TWO CONSECUTIVE 1KB
//                     wave-instrs per row (2KB DRAM runs) -- tests the
//                     "short strided runs cap reads at ~3TB/s" theory.
//                     Partials stored as f16 (halves partial traffic).
//   B) reduce_kernel: sum 128 f16 chunk-partials -> ex[b], eg[b] (f32)
//   C) chain_kernel : softmax chain -> M = gamma*GA   (no identity; tiny fp32)
//   D) apply_kernel : out[b] = M[b] @ x_b + x_b via MFMA f16 (fp32 residual)
// ---------------------------------------------------------------------------

typedef _Float16 h8 __attribute__((ext_vector_type(8)));
typedef float    f4 __attribute__((ext_vector_type(4)));
typedef __fp16   p2 __attribute__((ext_vector_type(2)));   // cvt_pkrtz result
typedef unsigned long long ull;

#define NB 16
#define NC 64
#define NPIX 65536
#define GRAM_CHUNK 512                  // pixels per gram block
#define NCHUNK (NPIX / GRAM_CHUNK)      // 128
#define ROW_H 520                       // halves/row (1040B = 260dw = 4 mod 32)
#define LDS_H (64 * ROW_H)              // 33280 halves = 66560 B

#define AP_NPX 256                      // apply: pixels per block
#define XT_ROW 72                       // apply: xT row stride in halves (144B)

__device__ __forceinline__ unsigned int pk(float a, float b) {
    p2 v = __builtin_amdgcn_cvt_pkrtz(a, b);
    return __builtin_bit_cast(unsigned int, v);
}

// ---- Kernel A: partial Gram matrices via MFMA, 2KB-run staging ------------
// grid (128, 16, 2): chunk, batch, matrix. 256 threads = 4 waves.
// Stage: wave w owns rows [16w, 16w+16); per row, its two 1KB load instrs
// are CONSECUTIVE in program order -> 2KB contiguous DRAM run before the
// 256KB row jump. Consume: wave w = A row-block w, 16 K-steps, acc[4].
__global__ __launch_bounds__(256) void gram_kernel(
    const float* __restrict__ x, const float* __restrict__ g,
    _Float16* __restrict__ part)
{
    __shared__ __align__(16) _Float16 buf[LDS_H];

    const int tid = threadIdx.x;
    const int mtx = blockIdx.z;
    const float* src = (mtx ? g : x)
        + (size_t)blockIdx.y * NC * NPIX + (size_t)blockIdx.x * GRAM_CHUNK;

    const int w    = tid >> 6;
    const int lane = tid & 63;

    // ---- stage: 16 rows/wave, 2 consecutive 1KB instrs per row ----
    #pragma unroll
    for (int rr = 0; rr < 16; ++rr) {
        const int r = w * 16 + rr;
        const float* rp = src + (size_t)r * NPIX + lane * 4;
        f4 va = *(const f4*)(rp);            // px [lane*4   .. lane*4+3]
        f4 vb = *(const f4*)(rp + 256);      // px [256+lane*4 .. ]  (+1KB)
        ull ha = (ull)pk(va.x, va.y) | ((ull)pk(va.z, va.w) << 32);
        ull hb = (ull)pk(vb.x, vb.y) | ((ull)pk(vb.z, vb.w) << 32);
        *reinterpret_cast<ull*>(&buf[r * ROW_H + lane * 4])       = ha;
        *reinterpret_cast<ull*>(&buf[r * ROW_H + 256 + lane * 4]) = hb;
    }
    __syncthreads();   // the only barrier

    // ---- consume: 16 K-steps x (1 A-frag + 4 B-frags + 4 MFMA) ----
    const int l15   = lane & 15;
    const int khalf = lane >> 4;
    const int abase = (w * 16 + l15) * ROW_H;

    f4 acc[4];
    #pragma unroll
    for (int cb = 0; cb < 4; ++cb) acc[cb] = (f4){0.f, 0.f, 0.f, 0.f};

    #pragma unroll
    for (int ks = 0; ks < 16; ++ks) {
        int koff = ks * 32 + khalf * 8;
        h8 a = *reinterpret_cast<const h8*>(&buf[abase + koff]);
        #pragma unroll
        for (int cb = 0; cb < 4; ++cb) {
            h8 bf = *reinterpret_cast<const h8*>(&buf[(cb * 16 + l15) * ROW_H + koff]);
            acc[cb] = __builtin_amdgcn_mfma_f32_16x16x32_f16(a, bf, acc[cb], 0, 0, 0);
        }
    }

    // ---- f16 partial store (33.5 MB total instead of 134 MB f32) ----
    _Float16* po = part + (((size_t)blockIdx.x * NB + blockIdx.y) * 2 + mtx) * 4096;
    #pragma unroll
    for (int cb = 0; cb < 4; ++cb)
        #pragma unroll
        for (int r = 0; r < 4; ++r)
            po[(w * 16 + khalf * 4 + r) * 64 + cb * 16 + l15] = (_Float16)acc[cb][r];
}

// ---- Kernel B: reduce 128 f16 chunk-partials -> ex, eg (f32) ---------------
__global__ __launch_bounds__(256) void reduce_kernel(
    const _Float16* __restrict__ part, float* __restrict__ ex, float* __restrict__ eg)
{
    const int idx = blockIdx.x * 256 + threadIdx.x;
    const int bm = idx >> 12;          // b*2 + m
    const int cd = idx & 4095;
    float s = 0.f;
    #pragma unroll 8
    for (int ch = 0; ch < NCHUNK; ++ch)
        s += (float)part[(size_t)ch * (NB * 2 * 4096) + (size_t)bm * 4096 + cd];
    float* dst = (bm & 1) ? eg : ex;
    dst[(bm >> 1) * 4096 + cd] = s;
}

// ---- Kernel C: softmax chain -> M = gamma*GA (no identity) ----------------
__global__ __launch_bounds__(256) void chain_kernel(
    const float* __restrict__ ex, const float* __restrict__ eg,
    const float* __restrict__ gammap, float* __restrict__ M)
{
    __shared__ float A1[64][68];
    __shared__ float A2[64][68];
    __shared__ float red[64][4];

    const int b = blockIdx.x;
    const int tid = threadIdx.x;

    if (tid < 64) {
        const int c = tid;
        float r[64];
        #pragma unroll
        for (int d = 0; d < 64; ++d) r[d] = ex[b * 4096 + c * 64 + d];
        float mx = r[0];
        #pragma unroll
        for (int d = 1; d < 64; ++d) mx = fmaxf(mx, r[d]);
        float s = 0.f;
        #pragma unroll
        for (int d = 0; d < 64; ++d) { r[d] = expf(r[d] - mx); s += r[d]; }
        float inv = 1.f / s;
        #pragma unroll
        for (int d = 0; d < 64; ++d) A1[c][d] = r[d] * inv;

        #pragma unroll
        for (int d = 0; d < 64; ++d) r[d] = eg[b * 4096 + c * 64 + d];
        mx = r[0];
        #pragma unroll
        for (int d = 1; d < 64; ++d) mx = fmaxf(mx, r[d]);
        s = 0.f;
        #pragma unroll
        for (int d = 0; d < 64; ++d) { r[d] = expf(r[d] - mx); s += r[d]; }
        inv = 1.f / s;
        #pragma unroll
        for (int d = 0; d < 64; ++d) A2[c][d] = r[d] * inv;
    }
    __syncthreads();

    const int c = tid >> 2, sq = tid & 3;
    float ge[16];
    #pragma unroll
    for (int k = 0; k < 16; ++k) ge[k] = 0.f;
    for (int d = 0; d < 64; ++d) {
        float a = A1[c][d];
        const float* row = &A2[d][sq * 16];
        #pragma unroll
        for (int k = 0; k < 16; ++k) ge[k] = fmaf(a, row[k], ge[k]);
    }

    float mx = ge[0];
    #pragma unroll
    for (int k = 1; k < 16; ++k) mx = fmaxf(mx, ge[k]);
    red[c][sq] = mx;
    __syncthreads();
    float gm = fmaxf(fmaxf(red[c][0], red[c][1]), fmaxf(red[c][2], red[c][3]));
    __syncthreads();

    float gen[16];
    #pragma unroll
    for (int k = 0; k < 16; ++k) gen[k] = gm - ge[k];
    float mx2 = gen[0];
    #pragma unroll
    for (int k = 1; k < 16; ++k) mx2 = fmaxf(mx2, gen[k]);
    red[c][sq] = mx2;
    __syncthreads();
    float m2 = fmaxf(fmaxf(red[c][0], red[c][1]), fmaxf(red[c][2], red[c][3]));
    __syncthreads();

    float p[16];
    float s = 0.f;
    #pragma unroll
    for (int k = 0; k < 16; ++k) { p[k] = expf(gen[k] - m2); s += p[k]; }
    red[c][sq] = s;
    __syncthreads();
    float S = red[c][0] + red[c][1] + red[c][2] + red[c][3];

    float gam = gammap[0];
    float invS = 1.f / S;
    #pragma unroll
    for (int k = 0; k < 16; ++k) {
        int e = sq * 16 + k;
        M[b * 4096 + c * 64 + e] = gam * p[k] * invS;   // NO +I: residual in apply
    }
}

// ---- Kernel D: out[b] = M[b] @ x[b] + x[b] via MFMA ------------------------
__global__ __launch_bounds__(256) void apply_kernel(
    const float* __restrict__ x, const float* __restrict__ M,
    float* __restrict__ out)
{
    __shared__ __align__(16) _Float16 xT[AP_NPX * XT_ROW];   // 36864 B
    __shared__ __align__(16) _Float16 Ml[64 * XT_ROW];       //  9216 B

    const int tid = threadIdx.x;
    const int b = blockIdx.y;
    const int n0 = blockIdx.x * AP_NPX;
    const float* xb = x + (size_t)b * NC * NPIX + n0;

    #pragma unroll
    for (int it = 0; it < 8; ++it) {
        int e = it * 256 + tid;
        int q  = e & 63;          // f4 col (4 pixels)
        int dp = e >> 6;          // d-pair 0..31
        f4 va = *(const f4*)(xb + (size_t)(2 * dp)     * NPIX + q * 4);
        f4 vb = *(const f4*)(xb + (size_t)(2 * dp + 1) * NPIX + q * 4);
        #pragma unroll
        for (int j = 0; j < 4; ++j) {
            float aj = (j == 0) ? va.x : (j == 1) ? va.y : (j == 2) ? va.z : va.w;
            float bj = (j == 0) ? vb.x : (j == 1) ? vb.y : (j == 2) ? vb.z : vb.w;
            *reinterpret_cast<unsigned int*>(&xT[(q * 4 + j) * XT_ROW + 2 * dp]) = pk(aj, bj);
        }
    }
    const float* Mb = M + b * 4096;
    #pragma unroll
    for (int it = 0; it < 4; ++it) {
        int e = it * 256 + tid;
        int c  = e >> 4;
        int qq = e & 15;
        f4 mv = *(const f4*)(Mb + c * 64 + qq * 4);
        *reinterpret_cast<unsigned int*>(&Ml[c * XT_ROW + qq * 4])     = pk(mv.x, mv.y);
        *reinterpret_cast<unsigned int*>(&Ml[c * XT_ROW + qq * 4 + 2]) = pk(mv.z, mv.w);
    }
    __syncthreads();

    const int w    = tid >> 6;
    const int lane = tid & 63;
    const int l15  = lane & 15;
    const int kh   = lane >> 4;

    h8 bfrag[4][2];
    #pragma unroll
    for (int nb = 0; nb < 4; ++nb)
        #pragma unroll
        for (int ks = 0; ks < 2; ++ks)
            bfrag[nb][ks] = *reinterpret_cast<const h8*>(
                &xT[(w * 64 + nb * 16 + l15) * XT_ROW + ks * 32 + kh * 8]);

    f4 acc[4][4];   // [cb][nb]
    #pragma unroll
    for (int cb = 0; cb < 4; ++cb)
        #pragma unroll
        for (int nb = 0; nb < 4; ++nb) acc[cb][nb] = (f4){0.f, 0.f, 0.f, 0.f};

    #pragma unroll
    for (int cb = 0; cb < 4; ++cb) {
        #pragma unroll
        for (int ks = 0; ks < 2; ++ks) {
            h8 a = *reinterpret_cast<const h8*>(
                &Ml[(cb * 16 + l15) * XT_ROW + ks * 32 + kh * 8]);
            #pragma unroll
            for (int nb = 0; nb < 4; ++nb)
                acc[cb][nb] = __builtin_amdgcn_mfma_f32_16x16x32_f16(a, bfrag[nb][ks], acc[cb][nb], 0, 0, 0);
        }
    }

    const size_t base = (size_t)b * NC * NPIX + n0 + w * 64;
    #pragma unroll
    for (int cb = 0; cb < 4; ++cb) {
        #pragma unroll
        for (int r = 0; r < 4; ++r) {
            const int row = cb * 16 + kh * 4 + r;
            #pragma unroll
            for (int nb = 0; nb < 4; ++nb) {
                size_t idx = base + (size_t)row * NPIX + nb * 16 + l15;
                out[idx] = acc[cb][nb][r] + x[idx];
            }
        }
    }
}

extern "C" void kernel_launch(void* const* d_in, const int* in_sizes, int n_in,
                              void* d_out, int out_size, void* d_ws, size_t ws_size,
                              hipStream_t stream) {
    const float* x     = (const float*)d_in[0];
    const float* g     = (const float*)d_in[1];
    const float* gamma = (const float*)d_in[2];
    float* out = (float*)d_out;
    float* ws  = (float*)d_ws;

    float* ex = ws;                  // 16*4096 floats
    float* eg = ws + NB * 4096;      // 16*4096 floats
    float* M  = ws + 2 * NB * 4096;  // 16*4096 floats

    // d_out doubles as scratch for the 33.5 MB f16 gram partials; apply
    // fully overwrites d_out afterwards (stream-ordered), so this is safe.
    _Float16* part = (_Float16*)out;

    gram_kernel<<<dim3(NCHUNK, NB, 2), 256, 0, stream>>>(x, g, part);
    reduce_kernel<<<512, 256, 0, stream>>>(part, ex, eg);
    chain_kernel<<<NB, 256, 0, stream>>>(ex, eg, gamma, M);
    apply_kernel<<<dim3(NPIX / AP_NPX, NB), 256, 0, stream>>>(x, M, out);
}